// Round 6
// baseline (860.440 us; speedup 1.0000x reference)
//
#include <hip/hip_runtime.h>
#include <hip/hip_bf16.h>
#include <cstdint>

// Problem constants (B,S,E,H) = (4, 2048, 256, 8), fp32 in/out.
#define B_N 4
#define S_N 2048
#define E_N 256
#define H_N 8

typedef float f32x4 __attribute__((ext_vector_type(4)));
typedef short s16x8 __attribute__((ext_vector_type(8)));   // 8 bf16 as shorts (4 VGPR)

static __device__ __forceinline__ f32x4 mfma16(s16x8 a, s16x8 b, f32x4 c) {
  return __builtin_amdgcn_mfma_f32_16x16x32_bf16(a, b, c, 0, 0, 0);
}

// fp32 <-> bf16 (RNE) bit ops.
static __device__ __forceinline__ unsigned short f2bf(float f) {
  union { float f; unsigned int u; } v; v.f = f;
  unsigned int r = v.u + 0x7fffu + ((v.u >> 16) & 1u);
  return (unsigned short)(r >> 16);
}
static __device__ __forceinline__ float bf2f(unsigned short s) {
  union { unsigned int u; float f; } v; v.u = ((unsigned int)s) << 16;
  return v.f;
}
static __device__ __forceinline__ unsigned short f2bf_fast(float f) {
  __hip_bfloat16 h = __float2bfloat16(f);
  return *(unsigned short*)&h;
}

// Async global->LDS, 16B per lane. LDS dest: wave-uniform base + lane*16.
static __device__ __forceinline__ void gload16(const void* g, void* l) {
  __builtin_amdgcn_global_load_lds(
      (const __attribute__((address_space(1))) unsigned int*)g,
      (__attribute__((address_space(3))) unsigned int*)l, 16, 0, 0);
}

// 16-lane (DPP-row) butterfly reduces — pure VALU, no LDS unit.
static __device__ __forceinline__ float dppmax16(float x) {
  x = fmaxf(x, __int_as_float(__builtin_amdgcn_update_dpp(
          0, __float_as_int(x), 0xB1, 0xF, 0xF, true)));   // xor 1
  x = fmaxf(x, __int_as_float(__builtin_amdgcn_update_dpp(
          0, __float_as_int(x), 0x4E, 0xF, 0xF, true)));   // xor 2
  x = fmaxf(x, __int_as_float(__builtin_amdgcn_update_dpp(
          0, __float_as_int(x), 0x141, 0xF, 0xF, true)));  // xor 4
  x = fmaxf(x, __int_as_float(__builtin_amdgcn_update_dpp(
          0, __float_as_int(x), 0x140, 0xF, 0xF, true)));  // xor 8
  return x;
}
static __device__ __forceinline__ float dppsum16(float x) {
  x = x + __int_as_float(__builtin_amdgcn_update_dpp(
          0, __float_as_int(x), 0xB1, 0xF, 0xF, true));
  x = x + __int_as_float(__builtin_amdgcn_update_dpp(
          0, __float_as_int(x), 0x4E, 0xF, 0xF, true));
  x = x + __int_as_float(__builtin_amdgcn_update_dpp(
          0, __float_as_int(x), 0x141, 0xF, 0xF, true));
  x = x + __int_as_float(__builtin_amdgcn_update_dpp(
          0, __float_as_int(x), 0x140, 0xF, 0xF, true));
  return x;
}

// ---------------------------------------------------------------------------
// Split fp32 -> bf16 hi + bf16 lo.
__global__ void k_split(const float* __restrict__ src, unsigned short* __restrict__ hi,
                        unsigned short* __restrict__ lo, int n4) {
  int i = blockIdx.x * blockDim.x + threadIdx.x;
  if (i >= n4) return;
  float4 v = ((const float4*)src)[i];
  float f[4] = {v.x, v.y, v.z, v.w};
  unsigned short hh[4], ll[4];
#pragma unroll
  for (int j = 0; j < 4; j++) {
    hh[j] = f2bf(f[j]);
    ll[j] = f2bf(f[j] - bf2f(hh[j]));
  }
  ushort4 h; h.x = hh[0]; h.y = hh[1]; h.z = hh[2]; h.w = hh[3];
  ushort4 l; l.x = ll[0]; l.y = ll[1]; l.z = ll[2]; l.w = ll[3];
  ((ushort4*)hi)[i] = h;
  ((ushort4*)lo)[i] = l;
}

// ---------------------------------------------------------------------------
// WvT[h][f][e] = bf16(Wv[h][e][f])
__global__ void k_transpose_wv(const float* __restrict__ wv, unsigned short* __restrict__ wvT) {
  __shared__ float t[32][33];
  int h = blockIdx.z;
  int e0 = blockIdx.x * 32, f0 = blockIdx.y * 32;
  int tx = threadIdx.x & 31, ty = threadIdx.x >> 5;
  const float* src = wv + ((size_t)h * E_N + e0) * E_N + f0;
#pragma unroll
  for (int r = ty; r < 32; r += 8) t[r][tx] = src[(size_t)r * E_N + tx];
  __syncthreads();
  unsigned short* dst = wvT + ((size_t)h * E_N + f0) * E_N + e0;
#pragma unroll
  for (int r = ty; r < 32; r += 8) dst[(size_t)r * E_N + tx] = f2bf(t[tx][r]);
}

// ---------------------------------------------------------------------------
// bt-GEMM: C[m,n] = sum_k A[m,k]*B[n,k], 128x128 tile, BK=32, 4 waves.
#define BKP 40  // 32 + 8 pad

template <int TERMS, int SPLIT_OUT>
__global__ __launch_bounds__(256, 2) void k_gemm(
    const unsigned short* __restrict__ Ahi, const unsigned short* __restrict__ Alo,
    const unsigned short* __restrict__ Bhi, const unsigned short* __restrict__ Blo,
    unsigned short* __restrict__ Chi, unsigned short* __restrict__ Clo,
    int K, int N,
    int aDiv, int aMod, long long aStr,
    int bDiv, int bMod, long long bStr,
    long long cStr) {
  __shared__ unsigned short sA[2][128 * BKP];
  __shared__ unsigned short sB[2][128 * BKP];
  int z = blockIdx.z;
  const unsigned short* A0h = Ahi + (long long)((z / aDiv) % aMod) * aStr;
  const unsigned short* A0l = Alo + (long long)((z / aDiv) % aMod) * aStr;
  const unsigned short* B0h = Bhi + (long long)((z / bDiv) % bMod) * bStr;
  const unsigned short* B0l = Blo + (long long)((z / bDiv) % bMod) * bStr;
  int rT = blockIdx.x * 128, cT = blockIdx.y * 128;
  int tid = threadIdx.x;
  int w = tid >> 6, l = tid & 63, lr = l & 15, lg = l >> 4;
  int wr = w >> 1, wc = w & 1;

  f32x4 acc[4][4];
#pragma unroll
  for (int i = 0; i < 4; i++)
#pragma unroll
    for (int j = 0; j < 4; j++) acc[i][j] = (f32x4){0.f, 0.f, 0.f, 0.f};

  for (int k0 = 0; k0 < K; k0 += 32) {
#pragma unroll
    for (int it = 0; it < 2; it++) {
      int idx = (it * 256 + tid) * 8;
      int r = idx >> 5, c = idx & 31;
      *(s16x8*)&sA[0][r * BKP + c] = *(const s16x8*)(A0h + (size_t)(rT + r) * K + k0 + c);
      *(s16x8*)&sB[0][r * BKP + c] = *(const s16x8*)(B0h + (size_t)(cT + r) * K + k0 + c);
      if (TERMS == 3) {
        *(s16x8*)&sA[1][r * BKP + c] = *(const s16x8*)(A0l + (size_t)(rT + r) * K + k0 + c);
        *(s16x8*)&sB[1][r * BKP + c] = *(const s16x8*)(B0l + (size_t)(cT + r) * K + k0 + c);
      }
    }
    __syncthreads();
    s16x8 ah[4], al[4], bh[4], bl[4];
#pragma unroll
    for (int i = 0; i < 4; i++) {
      ah[i] = *(const s16x8*)&sA[0][(wr * 64 + i * 16 + lr) * BKP + lg * 8];
      if (TERMS == 3) al[i] = *(const s16x8*)&sA[1][(wr * 64 + i * 16 + lr) * BKP + lg * 8];
    }
#pragma unroll
    for (int j = 0; j < 4; j++) {
      bh[j] = *(const s16x8*)&sB[0][(wc * 64 + j * 16 + lr) * BKP + lg * 8];
      if (TERMS == 3) bl[j] = *(const s16x8*)&sB[1][(wc * 64 + j * 16 + lr) * BKP + lg * 8];
    }
#pragma unroll
    for (int i = 0; i < 4; i++)
#pragma unroll
      for (int j = 0; j < 4; j++) {
        acc[i][j] = mfma16(ah[i], bh[j], acc[i][j]);
        if (TERMS == 3) {
          acc[i][j] = mfma16(ah[i], bl[j], acc[i][j]);
          acc[i][j] = mfma16(al[i], bh[j], acc[i][j]);
        }
      }
    __syncthreads();
  }
  long long cOff = (long long)z * cStr;
#pragma unroll
  for (int i = 0; i < 4; i++)
#pragma unroll
    for (int j = 0; j < 4; j++)
#pragma unroll
      for (int r = 0; r < 4; r++) {
        int row = rT + wr * 64 + i * 16 + lg * 4 + r;  // C/D: row=(l>>4)*4+reg
        int col = cT + wc * 64 + j * 16 + lr;          //      col=l&15
        float v = acc[i][j][r];
        unsigned short hb = f2bf(v);
        Chi[cOff + (size_t)row * N + col] = hb;
        if (SPLIT_OUT) Clo[cOff + (size_t)row * N + col] = f2bf(v - bf2f(hb));
      }
}

// ---------------------------------------------------------------------------
// Fused flash attention, round 6: 32 q-rows per wave (2 row-fragments).
// Block = 8 waves x 32 q = 256 q-rows; grid = 8 qt x 32 bh = 256 = 1 block/CU.
// Same LDS reads per wave per tile as R5 now serve 2x the MFMAs; VT B-frags
// hoisted across the two row-fragments in PV.
// LDS map (bytes):
//   [0,32768)        X hi [64 t][512B], stored byte = logical ^ ((row&7)<<4)
//   [32768,65536)    X lo (same swizzle)
//   [65536,98304)    VT [256 f][128B],  stored byte = logical ^ ((row&7)<<4)
//   [98304,131072)   P: per wave 4KB [32 q][128B], stored ^ (((row>>2)&3)<<4)
#define TT 64
#define ATTN_LDS 131072

__global__ __launch_bounds__(512, 1) void k_attn(
    const unsigned short* __restrict__ Yhi, const unsigned short* __restrict__ Ylo,
    const unsigned short* __restrict__ Xhi, const unsigned short* __restrict__ Xlo,
    const unsigned short* __restrict__ VT, float* __restrict__ Out) {
  extern __shared__ char smem[];

  // XCD-chunked swizzle: 256 blocks = 8 XCD * 32; per XCD: 4 bh x 8 qt.
  int obid = blockIdx.x;
  int swz = (obid & 7) * 32 + (obid >> 3);
  int qt = swz & 7, bh = swz >> 3;
  int b = bh >> 3;
  int tid = threadIdx.x, w = tid >> 6, l = tid & 63, lr = l & 15, lg = l >> 4;
  const unsigned short* Ybh_h = Yhi + (size_t)bh * (S_N * E_N);
  const unsigned short* Ybh_l = Ylo + (size_t)bh * (S_N * E_N);
  const unsigned short* Xb_h = Xhi + (size_t)b * (S_N * E_N);
  const unsigned short* Xb_l = Xlo + (size_t)b * (S_N * E_N);
  const unsigned short* Vbh = VT + (size_t)bh * (E_N * S_N);
  int qrow = qt * 256 + w * 32;  // wave owns rows [qrow, qrow+32)

  // Staging source descriptors (inverse-swizzled global element offsets).
  int xsrc[4], vsrc[4];
#pragma unroll
  for (int i = 0; i < 4; i++) {
    int c = w * 4 + i;
    int row = 2 * c + (l >> 5), byt = (l & 31) * 16;
    xsrc[i] = row * E_N + ((byt ^ ((row & 7) << 4)) >> 1);
    int vrow = 8 * c + (l >> 3), vbyt = (l & 7) * 16;
    vsrc[i] = vrow * S_N + ((vbyt ^ ((vrow & 7) << 4)) >> 1);
  }

  // Hoisted LDS base addresses (all kt-invariant).
  int xkb[8];
#pragma unroll
  for (int kc = 0; kc < 8; kc++)
    xkb[kc] = lr * 512 + ((kc * 64 + lg * 16) ^ ((lr & 7) << 4));
  int vtb[2];
#pragma unroll
  for (int tc = 0; tc < 2; tc++)
    vtb[tc] = 65536 + lr * 128 + ((tc * 64 + lg * 16) ^ ((lr & 7) << 4));
  // P swizzle key is invariant to the row-fragment bit (i*16): key = (row>>2)&3.
  int prb = 98304 + w * 4096 + lr * 128 + ((lg * 16) ^ (((lr >> 2) & 3) << 4));
  int pwb = 98304 + w * 4096 + lg * 512;  // + i*2048 + r*128 + swizzled byte

  // Hoist Y fragments (2 row-frags x 16 rows x K=256, hi+lo) into registers.
  s16x8 yh[2][8], yl[2][8];
#pragma unroll
  for (int i = 0; i < 2; i++)
#pragma unroll
    for (int kc = 0; kc < 8; kc++) {
      yh[i][kc] = *(const s16x8*)(Ybh_h + (size_t)(qrow + i * 16 + lr) * E_N + kc * 32 + lg * 8);
      yl[i][kc] = *(const s16x8*)(Ybh_l + (size_t)(qrow + i * 16 + lr) * E_N + kc * 32 + lg * 8);
    }
  f32x4 o0[16], o1[16];
#pragma unroll
  for (int i = 0; i < 16; i++) {
    o0[i] = (f32x4){0.f, 0.f, 0.f, 0.f};
    o1[i] = (f32x4){0.f, 0.f, 0.f, 0.f};
  }
  float m2[2][4], lv[2][4];
#pragma unroll
  for (int i = 0; i < 2; i++)
#pragma unroll
    for (int r = 0; r < 4; r++) { m2[i][r] = -3.0e38f; lv[i][r] = 0.f; }

  const float C2 = 0.09016844005556021f;  // (1/16) * log2(e)

  for (int kt = 0; kt < S_N / TT; kt++) {
    __builtin_amdgcn_s_barrier();  // B1: all waves done reading previous tile

    // Stage X[kt] (hi+lo) and VT[kt] via async global->LDS.
#pragma unroll
    for (int i = 0; i < 4; i++) {
      int c = w * 4 + i;
      gload16(Xb_h + (size_t)kt * (TT * E_N) + xsrc[i], smem + c * 1024);
      gload16(Xb_l + (size_t)kt * (TT * E_N) + xsrc[i], smem + 32768 + c * 1024);
      gload16(Vbh + kt * TT + vsrc[i], smem + 65536 + c * 1024);
    }
    asm volatile("s_waitcnt vmcnt(0)" ::: "memory");
    __builtin_amdgcn_s_barrier();  // B2: staged data visible to all waves

    // S = Y . X^T (3-term split): one X read pair feeds both row-fragments.
    f32x4 sc[2][4];
    __builtin_amdgcn_s_setprio(1);
#pragma unroll
    for (int j = 0; j < 4; j++) {
      f32x4 a0 = (f32x4){0.f, 0.f, 0.f, 0.f};
      f32x4 a1 = (f32x4){0.f, 0.f, 0.f, 0.f};
#pragma unroll
      for (int kc = 0; kc < 8; kc++) {
        s16x8 xh = *(const s16x8*)(smem + xkb[kc] + j * 8192);
        s16x8 xl = *(const s16x8*)(smem + xkb[kc] + j * 8192 + 32768);
        a0 = mfma16(yh[0][kc], xh, a0);
        a0 = mfma16(yh[0][kc], xl, a0);
        a0 = mfma16(yl[0][kc], xh, a0);
        a1 = mfma16(yh[1][kc], xh, a1);
        a1 = mfma16(yh[1][kc], xl, a1);
        a1 = mfma16(yl[1][kc], xh, a1);
      }
      sc[0][j] = a0;
      sc[1][j] = a1;
    }
    __builtin_amdgcn_s_setprio(0);

    // Online softmax, log2 domain. Lane: rows i*16+lg*4+r, cols j*16+lr.
    float t2[2][4];
#pragma unroll
    for (int i = 0; i < 2; i++)
#pragma unroll
      for (int r = 0; r < 4; r++)
        t2[i][r] = fmaxf(fmaxf(sc[i][0][r], sc[i][1][r]),
                         fmaxf(sc[i][2][r], sc[i][3][r])) * C2;

    bool ok = true;
#pragma unroll
    for (int i = 0; i < 2; i++)
#pragma unroll
      for (int r = 0; r < 4; r++) ok = ok && (t2[i][r] <= m2[i][r] + 8.f);
    if (!__all(ok)) {
      float fr[2][4];
#pragma unroll
      for (int i = 0; i < 2; i++)
#pragma unroll
        for (int r = 0; r < 4; r++) {
          float rm = dppmax16(t2[i][r]);
          float nm = fmaxf(m2[i][r], rm);
          fr[i][r] = exp2f(m2[i][r] - nm);
          m2[i][r] = nm;
          lv[i][r] *= fr[i][r];
        }
#pragma unroll
      for (int jf = 0; jf < 16; jf++)
#pragma unroll
        for (int r = 0; r < 4; r++) {
          o0[jf][r] *= fr[0][r];
          o1[jf][r] *= fr[1][r];
        }
    }

    float p[2][4][4];
#pragma unroll
    for (int i = 0; i < 2; i++) {
#pragma unroll
      for (int j = 0; j < 4; j++)
#pragma unroll
        for (int r = 0; r < 4; r++)
          p[i][j][r] = exp2f(fmaf(sc[i][j][r], C2, -m2[i][r]));
#pragma unroll
      for (int r = 0; r < 4; r++)
        lv[i][r] += (p[i][0][r] + p[i][1][r]) + (p[i][2][r] + p[i][3][r]);
    }

    // P -> LDS bf16 (wave-private; stored byte = logical ^ (((row>>2)&3)<<4)).
#pragma unroll
    for (int i = 0; i < 2; i++)
#pragma unroll
      for (int j = 0; j < 4; j++)
#pragma unroll
        for (int r = 0; r < 4; r++) {
          int byt = (32 * j + 2 * lr) ^ (lg << 4);  // key bits for row lg*4+r
          *(unsigned short*)(smem + pwb + i * 2048 + r * 128 + byt) =
              f2bf_fast(p[i][j][r]);
        }

    // O += P . VT  (bt-form; bv hoisted across the two row-fragments).
    __builtin_amdgcn_s_setprio(1);
#pragma unroll
    for (int tc = 0; tc < 2; tc++) {
      s16x8 pa0 = *(const s16x8*)(smem + prb + tc * 64);
      s16x8 pa1 = *(const s16x8*)(smem + prb + 2048 + tc * 64);
#pragma unroll
      for (int jf = 0; jf < 16; jf++) {
        s16x8 bv = *(const s16x8*)(smem + vtb[tc] + jf * 2048);
        o0[jf] = mfma16(pa0, bv, o0[jf]);
        o1[jf] = mfma16(pa1, bv, o1[jf]);
      }
    }
    __builtin_amdgcn_s_setprio(0);
  }

  // Epilogue: finish lv sum-reduce, normalize, head-mean via atomics.
#pragma unroll
  for (int i = 0; i < 2; i++)
#pragma unroll
    for (int r = 0; r < 4; r++) lv[i][r] = dppsum16(lv[i][r]);
#pragma unroll
  for (int jf = 0; jf < 16; jf++)
#pragma unroll
    for (int r = 0; r < 4; r++) {
      size_t row0 = (size_t)b * S_N + qrow + lg * 4 + r;
      atomicAdd(&Out[(row0)*E_N + jf * 16 + lr], o0[jf][r] / lv[0][r] * 0.125f);
      atomicAdd(&Out[(row0 + 16) * E_N + jf * 16 + lr], o1[jf][r] / lv[1][r] * 0.125f);
    }
}

// ---------------------------------------------------------------------------
extern "C" void kernel_launch(void* const* d_in, const int* in_sizes, int n_in,
                              void* d_out, int out_size, void* d_ws, size_t ws_size,
                              hipStream_t stream) {
  const float* x = (const float*)d_in[0];
  const float* wq = (const float*)d_in[1];
  const float* wk = (const float*)d_in[2];
  const float* wv = (const float*)d_in[3];
  float* out = (float*)d_out;

  unsigned short* ws = (unsigned short*)d_ws;
  unsigned short* x_hi = ws;                       // [B,S,E]
  unsigned short* x_lo = x_hi + 2097152;
  unsigned short* wq_hi = x_lo + 2097152;          // [H,E,E]
  unsigned short* wq_lo = wq_hi + 524288;
  unsigned short* wk_hi = wq_lo + 524288;
  unsigned short* wk_lo = wk_hi + 524288;
  unsigned short* wvT = wk_lo + 524288;            // [H,E(f),E(e)]
  unsigned short* mt_hi = wvT + 524288;            // [H,E,E] = Wk.Wq^T
  unsigned short* mt_lo = mt_hi + 524288;
  unsigned short* y_hi = mt_lo + 524288;           // [B,H,S,E]
  unsigned short* y_lo = y_hi + 16777216;
  unsigned short* vt = y_lo + 16777216;            // [B,H,E(f),S(t)]

  hipMemsetAsync(d_out, 0, (size_t)out_size * sizeof(float), stream);

  k_split<<<2048, 256, 0, stream>>>(x, x_hi, x_lo, 524288);
  k_split<<<512, 256, 0, stream>>>(wq, wq_hi, wq_lo, 131072);
  k_split<<<512, 256, 0, stream>>>(wk, wk_hi, wk_lo, 131072);
  k_transpose_wv<<<dim3(8, 8, 8), 256, 0, stream>>>(wv, wvT);

  // MT_h = Wk_h . Wq_h^T
  k_gemm<3, 1><<<dim3(2, 2, 8), 256, 0, stream>>>(
      wk_hi, wk_lo, wq_hi, wq_lo, mt_hi, mt_lo, 256, 256,
      1, 8, 65536LL, 1, 8, 65536LL, 65536LL);
  // Y[b,h] = X_b . MT_h^T
  k_gemm<3, 1><<<dim3(16, 2, 32), 256, 0, stream>>>(
      x_hi, x_lo, mt_hi, mt_lo, y_hi, y_lo, 256, 256,
      8, 4, 524288LL, 1, 8, 65536LL, 524288LL);
  // VT[b,h] = WvT_h . X_b^T
  k_gemm<1, 0><<<dim3(2, 16, 32), 256, 0, stream>>>(
      wvT, wvT, x_hi, x_hi, vt, vt, 256, 2048,
      1, 8, 65536LL, 8, 4, 524288LL, 524288LL);

  hipFuncSetAttribute((const void*)k_attn, hipFuncAttributeMaxDynamicSharedMemorySize,
                      ATTN_LDS);
  k_attn<<<dim3(256), 512, ATTN_LDS, stream>>>(y_hi, y_lo, x_hi, x_lo, vt, out);
}